// Round 3
// baseline (173.009 us; speedup 1.0000x reference)
//
#include <hip/hip_runtime.h>

// Output: (B=512, H=128, W=128, C=5) fp32.
// ch0 = stamp[h,w]; ch1 = scatter-add (fused via LDS before flush); ch2 = x[b,h>>2];
// ch3 = |x[b,h>>2]-x[b,w>>2]| / (max-min); ch4 = bar (col 17+3i is bar i, h<bh[i]).
//
// Block = (b, part): 1024 pixels = rows [part*8, part*8+8) of image b.
// Single 20 KB LDS staging buffer -> 8 blocks/CU (32 waves/CU).
// Scatter-add lands in LDS between the two barriers (no global atomics).
// Flush uses NONTEMPORAL float4 stores (native ext_vector_type -- the builtin
// rejects HIP_vector_type): output is write-once, bypass L2/LLC allocation.

typedef float f32x4 __attribute__((ext_vector_type(4)));

__global__ __launch_bounds__(256, 8) void di_main(const float* __restrict__ inputs,
                                                  const float* __restrict__ stamp,
                                                  const int* __restrict__ coords,
                                                  float* __restrict__ out) {
    const int blk  = blockIdx.x;     // 8192 blocks: 512 b x 16 parts
    const int b    = blk >> 4;
    const int part = blk & 15;
    const int tid  = threadIdx.x;
    const int lane = tid & 63;

    __shared__ float buf[256 * 20];  // 20 KB staging: 1024 px * 5 ch

    // ---- barrier-free preamble: per-wave redundant, all via shuffles ----
    const float v = inputs[b * 32 + (lane & 31)];   // lanes 32..63 duplicate
    int bt = (int)rintf(v * 128.0f);                // round-half-even = np.round
    bt = bt < 0 ? 0 : (bt > 128 ? 128 : bt);        // per-lane bar height
    float mn = v, mx = v;
#pragma unroll
    for (int off = 1; off < 32; off <<= 1) {        // within-half butterfly
        mn = fminf(mn, __shfl_xor(mn, off));
        mx = fmaxf(mx, __shfl_xor(mx, off));
    }
    const float inv = 1.0f / (mx - mn);             // dm min = 0 (diagonal)

    // ---- compute this thread's 4 pixels (one row each, consecutive w) ----
    const int lp = part * 1024 + tid * 4;           // global pixel index
    const int h  = lp >> 7;                         // global row
    const int w0 = lp & 127;                        // multiple of 4
    const float rowv = __shfl(v, h >> 2);
    const float ndv  = fabsf(rowv - v) * inv;       // w0>>2 == lane&31 -> col val is own v
    const float4 sv  = *reinterpret_cast<const float4*>(stamp + lp);
    const float svj[4] = {sv.x, sv.y, sv.z, sv.w};

    alignas(16) float vals[20];
#pragma unroll
    for (int j = 0; j < 4; ++j) {
        const int w = w0 + j;
        const int t = w - 17;
        const int bar = t / 3;
        const bool valid = (t >= 0) && (t <= 93) && (t - bar * 3 == 0);
        const int bhv = __shfl(bt, valid ? bar : 0);
        vals[5 * j + 0] = svj[j];
        vals[5 * j + 1] = 0.0f;                     // ch1 scatter added in LDS below
        vals[5 * j + 2] = rowv;
        vals[5 * j + 3] = ndv;
        vals[5 * j + 4] = (valid && h < bhv) ? 1.0f : 0.0f;
    }
    {
        float4* lw = reinterpret_cast<float4*>(&buf[tid * 20]);  // 80B, 16-aligned
        const float4* src = reinterpret_cast<const float4*>(vals);
#pragma unroll
        for (int k = 0; k < 5; ++k) lw[k] = src[k];
    }
    __syncthreads();

    // ---- fused scatter into LDS (duplicates sum via ds atomic) ----
    if (tid < 32) {
        const int2 rc = reinterpret_cast<const int2*>(coords)[tid];
        if ((rc.x >> 3) == part) {                  // block owns rows [part*8, part*8+8)
            const int pp = rc.x * 128 + rc.y - part * 1024;   // block-local pixel
            atomicAdd(&buf[(pp >> 2) * 20 + (pp & 3) * 5 + 1], v);  // v = x[b][tid]
        }
    }
    __syncthreads();

    // ---- flush: stride-1 float4 per lane -> contiguous 1024B full-line wave
    // stores, NONTEMPORAL (no L2/LLC allocate; output is write-once).
    f32x4* dst = reinterpret_cast<f32x4*>(out) +
                 (size_t)b * 20480 + (size_t)part * 1280;
    const f32x4* lr = reinterpret_cast<const f32x4*>(buf);
#pragma unroll
    for (int it = 0; it < 5; ++it) {
        const int f = it * 256 + tid;
        __builtin_nontemporal_store(lr[f], dst + f);
    }
}

extern "C" void kernel_launch(void* const* d_in, const int* in_sizes, int n_in,
                              void* d_out, int out_size, void* d_ws, size_t ws_size,
                              hipStream_t stream) {
    const float* inputs = (const float*)d_in[0];   // [512,32]
    const float* stamp  = (const float*)d_in[1];   // [128,128,1]
    const int*   coords = (const int*)d_in[2];     // [32,2]
    float* out = (float*)d_out;                    // [512,128,128,5]

    di_main<<<8192, 256, 0, stream>>>(inputs, stamp, coords, out);
}

// Round 4
// 165.031 us; speedup vs baseline: 1.0483x; 1.0483x over previous
//
#include <hip/hip_runtime.h>

// Output: (B=512, H=128, W=128, C=5) fp32.
// ch0 = stamp[h,w]; ch1 = scatter-add (fused via LDS before flush); ch2 = x[b,h>>2];
// ch3 = |x[b,h>>2]-x[b,w>>2]| / (max-min); ch4 = bar (col 17+3i is bar i, h<bh[i]).
//
// Block = (b, part): 1024 pixels = rows [part*8, part*8+8) of image b.
// Single 20 KB LDS staging buffer -> 8 blocks/CU (32 waves/CU).
// Scatter-add lands in LDS between the two barriers (no global atomics).
// Flush = plain (write-back) float4 stores: A/B vs nontemporal showed plain is
// ~5 µs faster (L2 write-combining absorbs full lines; nt forced per-line HBM).
//
// Roofline note: di_main ~= 26-30 us (167.8 MB write-once at ~6 TB/s); the
// timed 167 us total is dominated by the harness poison-fill (671 MB, ~105 us,
// itself at HBM ceiling) + fixed reset-dispatch overhead (~30 us).

__global__ __launch_bounds__(256, 8) void di_main(const float* __restrict__ inputs,
                                                  const float* __restrict__ stamp,
                                                  const int* __restrict__ coords,
                                                  float* __restrict__ out) {
    const int blk  = blockIdx.x;     // 8192 blocks: 512 b x 16 parts
    const int b    = blk >> 4;
    const int part = blk & 15;
    const int tid  = threadIdx.x;
    const int lane = tid & 63;

    __shared__ float buf[256 * 20];  // 20 KB staging: 1024 px * 5 ch

    // ---- barrier-free preamble: per-wave redundant, all via shuffles ----
    const float v = inputs[b * 32 + (lane & 31)];   // lanes 32..63 duplicate
    int bt = (int)rintf(v * 128.0f);                // round-half-even = np.round
    bt = bt < 0 ? 0 : (bt > 128 ? 128 : bt);        // per-lane bar height
    float mn = v, mx = v;
#pragma unroll
    for (int off = 1; off < 32; off <<= 1) {        // within-half butterfly
        mn = fminf(mn, __shfl_xor(mn, off));
        mx = fmaxf(mx, __shfl_xor(mx, off));
    }
    const float inv = 1.0f / (mx - mn);             // dm min = 0 (diagonal)

    // ---- compute this thread's 4 pixels (one row each, consecutive w) ----
    const int lp = part * 1024 + tid * 4;           // global pixel index
    const int h  = lp >> 7;                         // global row
    const int w0 = lp & 127;                        // multiple of 4
    const float rowv = __shfl(v, h >> 2);
    const float ndv  = fabsf(rowv - v) * inv;       // w0>>2 == lane&31 -> col val is own v
    const float4 sv  = *reinterpret_cast<const float4*>(stamp + lp);
    const float svj[4] = {sv.x, sv.y, sv.z, sv.w};

    alignas(16) float vals[20];
#pragma unroll
    for (int j = 0; j < 4; ++j) {
        const int w = w0 + j;
        const int t = w - 17;
        const int bar = t / 3;
        const bool valid = (t >= 0) && (t <= 93) && (t - bar * 3 == 0);
        const int bhv = __shfl(bt, valid ? bar : 0);
        vals[5 * j + 0] = svj[j];
        vals[5 * j + 1] = 0.0f;                     // ch1 scatter added in LDS below
        vals[5 * j + 2] = rowv;
        vals[5 * j + 3] = ndv;
        vals[5 * j + 4] = (valid && h < bhv) ? 1.0f : 0.0f;
    }
    {
        float4* lw = reinterpret_cast<float4*>(&buf[tid * 20]);  // 80B, 16-aligned
        const float4* src = reinterpret_cast<const float4*>(vals);
#pragma unroll
        for (int k = 0; k < 5; ++k) lw[k] = src[k];
    }
    __syncthreads();

    // ---- fused scatter into LDS (duplicates sum via ds atomic) ----
    if (tid < 32) {
        const int2 rc = reinterpret_cast<const int2*>(coords)[tid];
        if ((rc.x >> 3) == part) {                  // block owns rows [part*8, part*8+8)
            const int pp = rc.x * 128 + rc.y - part * 1024;   // block-local pixel
            atomicAdd(&buf[(pp >> 2) * 20 + (pp & 3) * 5 + 1], v);  // v = x[b][tid]
        }
    }
    __syncthreads();

    // ---- flush: stride-1 float4 per lane -> contiguous 1024B full-line wave
    // stores. No trailing barrier: stores drain at wave end.
    float4* dst = reinterpret_cast<float4*>(out) +
                  (size_t)b * 20480 + (size_t)part * 1280;
    const float4* lr = reinterpret_cast<const float4*>(buf);
#pragma unroll
    for (int it = 0; it < 5; ++it) {
        const int f = it * 256 + tid;
        dst[f] = lr[f];
    }
}

extern "C" void kernel_launch(void* const* d_in, const int* in_sizes, int n_in,
                              void* d_out, int out_size, void* d_ws, size_t ws_size,
                              hipStream_t stream) {
    const float* inputs = (const float*)d_in[0];   // [512,32]
    const float* stamp  = (const float*)d_in[1];   // [128,128,1]
    const int*   coords = (const int*)d_in[2];     // [32,2]
    float* out = (float*)d_out;                    // [512,128,128,5]

    di_main<<<8192, 256, 0, stream>>>(inputs, stamp, coords, out);
}